// Round 8
// baseline (67.869 us; speedup 1.0000x reference)
//
#include <hip/hip_runtime.h>

#define NN 8192
#define DD 256   // 512 bytes per bf16 row
#define NTILES 2080
#define NBLK 768

typedef __bf16 bf16x8 __attribute__((ext_vector_type(8)));
typedef float  f32x4  __attribute__((ext_vector_type(4)));

__device__ __forceinline__ unsigned short f2bf(float f) {
    unsigned u = __float_as_uint(f);
    return (unsigned short)((u + 0x7fffu + ((u >> 16) & 1u)) >> 16);
}

__device__ __forceinline__ void gload16(const void* g, void* l) {
    __builtin_amdgcn_global_load_lds((const __attribute__((address_space(1))) void*)g,
                                     (__attribute__((address_space(3))) void*)l,
                                     16, 0, 0);
}

// ---------------- kernel 1: normalize rows -> bf16, zero rowsum ----------------
__global__ __launch_bounds__(256) void ntxent_norm(const float* __restrict__ z,
                                                   char* __restrict__ znB,
                                                   float* __restrict__ rowsum)
{
    const int t = threadIdx.x;
    const int l = t & 63;
    const int w = t >> 6;
    const int row = blockIdx.x * 4 + w;

    float4 v = ((const float4*)(z + (size_t)row * DD))[l];
    float ss = v.x * v.x + v.y * v.y + v.z * v.z + v.w * v.w;
    ss += __shfl_xor(ss, 1);  ss += __shfl_xor(ss, 2);  ss += __shfl_xor(ss, 4);
    ss += __shfl_xor(ss, 8);  ss += __shfl_xor(ss, 16); ss += __shfl_xor(ss, 32);
    const float inv = 1.0f / fmaxf(sqrtf(ss), 1e-8f);

    uint2 o;
    o.x = (unsigned)f2bf(v.x * inv) | ((unsigned)f2bf(v.y * inv) << 16);
    o.y = (unsigned)f2bf(v.z * inv) | ((unsigned)f2bf(v.w * inv) << 16);
    ((uint2*)(znB + (size_t)row * 512))[l] = o;

    if (blockIdx.x < 32) rowsum[blockIdx.x * 256 + t] = 0.0f;
}

// ---------------- kernel 2: symmetric triangle, depth-2 counted-vmcnt pipeline ----
// 2080 lower-triangle 128x128 tiles over 768 blocks (3/CU), contiguous runs.
// BK=32: one chunk = A-half (128x64B) + B-half interleaved in 128-B physical rows
// [A0 A1 A2 A3 B0 B1 B2 B3] (16-B units), XOR-swizzled by (row&7) (true involution;
// per-16-lane fragment reads = 2 lanes/bank = free). Triple-buffered (3x16 KB):
// while computing chunk n, n+1 is resident/landing and n+2 is issued; step ends with
// s_waitcnt vmcnt(4) (waits n+1 only, issued a full step earlier) — never drains to 0
// except at the very end. Epilogue/atomics = R7 verbatim (row+col symmetric reduce).
__global__ __launch_bounds__(256) void ntxent_sim(const char* __restrict__ znB,
                                                  float* __restrict__ rowsum,
                                                  float* __restrict__ possum)
{
    __shared__ char sAB[3][16384];
    __shared__ float psh[4];

    const int t  = threadIdx.x;
    const int l  = t & 63;
    const int w  = t >> 6;      // wave 0..3
    const int wr = w >> 1;      // row half
    const int wc = w & 1;       // col half
    const int lm = l & 15;
    const int lh = l >> 4;      // 0..3

    const int arow0 = wr * 64;
    const int bcol0 = wc * 64;
    const f32x4 vzero = {0.0f, 0.0f, 0.0f, 0.0f};

    // contiguous tile range [t0, t1)
    const int t0 = (NTILES * blockIdx.x) / NBLK;
    const int t1 = (NTILES * (blockIdx.x + 1)) / NBLK;

    int rt = (int)((sqrtf(8.0f * (float)t0 + 1.0f) - 1.0f) * 0.5f);
    while ((rt + 1) * (rt + 2) / 2 <= t0) ++rt;
    while (rt * (rt + 1) / 2 > t0) --rt;
    int ct = t0 - rt * (rt + 1) / 2;

    // stage chunk bk (BK=32, 16 KB) of tile (rowbase,colbase) into buffer buf
    auto STAGE = [&](int buf, int rowbase, int colbase, int bk) {
#pragma unroll
        for (int p = 0; p < 4; ++p) {
            const int flat = p * 4096 + t * 16;        // dest: uniform + lane*16
            const int row  = flat >> 7;                // 0..127
            const int d    = (flat >> 4) & 7;          // physical 16B unit
            const int s    = d ^ (row & 7);            // logical unit (involution)
            const char* src = (s < 4)
                ? znB + (size_t)(rowbase + row) * 512 + bk * 64 + s * 16
                : znB + (size_t)(colbase + row) * 512 + bk * 64 + (s - 4) * 16;
            gload16(src, &sAB[buf][flat]);
        }
    };

    // prologue: chunks 0,1 of first tile
    STAGE(0, rt * 128, ct * 128, 0);
    STAGE(1, rt * 128, ct * 128, 1);
    asm volatile("s_waitcnt vmcnt(4)" ::: "memory");
    __syncthreads();
    int buf = 0;

#pragma unroll 1
    for (int tl = t0; tl < t1; ++tl) {
        const int rowbase = rt * 128;
        const int colbase = ct * 128;
        const bool diag = (rt == ct);
        const int nrt = (ct < rt) ? rt : rt + 1;       // next tile (triangle walk)
        const int nct = (ct < rt) ? ct + 1 : 0;
        const bool morettl = (tl + 1 < t1);

        f32x4 acc[4][4];
#pragma unroll
        for (int r = 0; r < 4; ++r)
#pragma unroll
            for (int c = 0; c < 4; ++c) acc[r][c] = vzero;

#pragma unroll
        for (int bk = 0; bk < 8; ++bk) {
            int nbuf = buf + 2; if (nbuf >= 3) nbuf -= 3;
            bool staged = true;
            if (bk < 6)        STAGE(nbuf, rowbase, colbase, bk + 2);
            else if (morettl)  STAGE(nbuf, nrt * 128, nct * 128, bk - 6);
            else               staged = false;

            const char* base = sAB[buf];
            bf16x8 af[4], bfr[4];
#pragma unroll
            for (int s = 0; s < 4; ++s) {
                const int ar = arow0 + s * 16 + lm;
                af[s]  = *(const bf16x8*)(base + ar * 128 + ((lh ^ (ar & 7)) << 4));
                const int bc = bcol0 + s * 16 + lm;
                bfr[s] = *(const bf16x8*)(base + bc * 128 + (((4 + lh) ^ (bc & 7)) << 4));
            }
#pragma unroll
            for (int r = 0; r < 4; ++r)
#pragma unroll
                for (int c = 0; c < 4; ++c)
                    acc[r][c] = __builtin_amdgcn_mfma_f32_16x16x32_bf16(af[r], bfr[c], acc[r][c], 0, 0, 0);

            // counted wait: chunk n+1 complete; just-issued n+2 stays in flight
            if (staged) { asm volatile("s_waitcnt vmcnt(4)" ::: "memory"); }
            else        { asm volatile("s_waitcnt vmcnt(0)" ::: "memory"); }
            __syncthreads();
            buf = (buf == 2) ? 0 : buf + 1;
        }

        // ---------------- epilogue: exp, row sums, col sums (symmetry), positives ----
        float rsum[16];
#pragma unroll
        for (int q = 0; q < 16; ++q) rsum[q] = 0.0f;
        float csum[4] = {0.0f, 0.0f, 0.0f, 0.0f};
        float psum = 0.0f;

#pragma unroll
        for (int r = 0; r < 4; ++r) {
            const int ib = rowbase + arow0 + r * 16 + lh * 4;
#pragma unroll
            for (int c = 0; c < 4; ++c) {
                const int j = colbase + bcol0 + c * 16 + lm;
#pragma unroll
                for (int q = 0; q < 4; ++q) {
                    const int i = ib + q;
                    const float lg = 2.0f * acc[r][c][q];
                    const float e = __expf(lg);
                    const float ev = (diag && (j == i)) ? 0.0f : e;
                    rsum[r * 4 + q] += ev;
                    csum[c] += ev;                                   // used iff !diag
                    if (diag) psum += (j == (i ^ 1)) ? lg : 0.0f;
                }
            }
        }

#pragma unroll
        for (int q = 0; q < 16; ++q) {
            float v = rsum[q];
            v += __shfl_xor(v, 1); v += __shfl_xor(v, 2);
            v += __shfl_xor(v, 4); v += __shfl_xor(v, 8);
            rsum[q] = v;
        }
        if (lm == 0) {
#pragma unroll
            for (int r = 0; r < 4; ++r)
#pragma unroll
                for (int q = 0; q < 4; ++q)
                    atomicAdd(&rowsum[rowbase + arow0 + r * 16 + lh * 4 + q], rsum[r * 4 + q]);
        }

        if (!diag) {
#pragma unroll
            for (int c = 0; c < 4; ++c) {
                float v = csum[c];
                v += __shfl_xor(v, 16); v += __shfl_xor(v, 32);
                if (lh == 0) atomicAdd(&rowsum[colbase + bcol0 + c * 16 + lm], v);
            }
        } else {
            float p = psum;
            p += __shfl_xor(p, 1);  p += __shfl_xor(p, 2);  p += __shfl_xor(p, 4);
            p += __shfl_xor(p, 8);  p += __shfl_xor(p, 16); p += __shfl_xor(p, 32);
            if (l == 0) psh[w] = p;
            __syncthreads();
            if (t == 0) possum[rt] = psh[0] + psh[1] + psh[2] + psh[3];
            __syncthreads();   // protect psh before any later diag tile reuses it
        }

        rt = nrt; ct = nct;
    }
}

// ---------------- kernel 3: final scalar ----------------
__global__ __launch_bounds__(512) void ntxent_final(const float* __restrict__ rowsum,
                                                    const float* __restrict__ possum,
                                                    float* __restrict__ out)
{
    __shared__ float sh[8];
    const int t = threadIdx.x;
    float s = 0.0f;
#pragma unroll
    for (int r = 0; r < 16; ++r) s += __logf(rowsum[r * 512 + t]);  // ILP: 16 indep loads
    if (t < 64) s -= possum[t];
    s += __shfl_xor(s, 1);  s += __shfl_xor(s, 2);  s += __shfl_xor(s, 4);
    s += __shfl_xor(s, 8);  s += __shfl_xor(s, 16); s += __shfl_xor(s, 32);
    if ((t & 63) == 0) sh[t >> 6] = s;
    __syncthreads();
    if (t == 0) {
        float a = 0.0f;
#pragma unroll
        for (int k = 0; k < 8; ++k) a += sh[k];
        out[0] = a * (1.0f / NN);
    }
}

extern "C" void kernel_launch(void* const* d_in, const int* in_sizes, int n_in,
                              void* d_out, int out_size, void* d_ws, size_t ws_size,
                              hipStream_t stream)
{
    const float* z = (const float*)d_in[0];
    char*  znB    = (char*)d_ws;
    float* rowsum = (float*)((char*)d_ws + (size_t)NN * 512);
    float* possum = (float*)((char*)d_ws + (size_t)NN * 512 + (size_t)NN * 4);
    float* out = (float*)d_out;

    ntxent_norm <<<dim3(NN / 4), dim3(256), 0, stream>>>(z, znB, rowsum);
    ntxent_sim  <<<dim3(NBLK),   dim3(256), 0, stream>>>(znB, rowsum, possum);
    ntxent_final<<<dim3(1),      dim3(512), 0, stream>>>(rowsum, possum, out);
}